// Round 3
// baseline (215.714 us; speedup 1.0000x reference)
//
#include <hip/hip_runtime.h>
#include <stdint.h>

#define B_ 8
#define T_ 1024
#define C_ 1024
#define H_ 16
#define HD 64
#define M_TOT (B_ * T_)  // 8192

using f32x4 = __attribute__((ext_vector_type(4))) float;
using s16x8 = __attribute__((ext_vector_type(8))) short;
using i32x4 = __attribute__((ext_vector_type(4))) int;

__device__ __forceinline__ unsigned short f2bf(float f) {
  unsigned int u = __builtin_bit_cast(unsigned int, f);
  unsigned int r = (u + 0x7fffu + ((u >> 16) & 1u)) >> 16;
  return (unsigned short)r;
}

__device__ __forceinline__ void gload_lds16(const void* g, void* l) {
  __builtin_amdgcn_global_load_lds(
      (const __attribute__((address_space(1))) unsigned int*)g,
      (__attribute__((address_space(3))) unsigned int*)l, 16, 0, 0);
}

// ---------------------------------------------------------------- convert
__global__ __launch_bounds__(256) void k_convert(
    const float* __restrict__ x, const float* __restrict__ wq,
    const float* __restrict__ wk, const float* __restrict__ wv,
    const float* __restrict__ wp, const float* __restrict__ bq,
    const float* __restrict__ bk, const float* __restrict__ bv,
    const int* __restrict__ maskp, unsigned short* __restrict__ xb,
    unsigned short* __restrict__ wqkv, unsigned short* __restrict__ wpb,
    float* __restrict__ bias_cat, unsigned int* __restrict__ mpair) {
  const long n_x = (long)M_TOT * C_;          // 8388608
  const long W_ELT = (long)C_ * C_;           // 1048576
  const long total4 = (n_x + 4 * W_ELT) >> 2; // 3145728
  for (long i4 = (long)blockIdx.x * blockDim.x + threadIdx.x; i4 < total4;
       i4 += (long)gridDim.x * blockDim.x) {
    long i = i4 << 2;
    const float* src;
    unsigned short* dst;
    if (i < n_x) {
      src = x + i;
      dst = xb + i;
    } else {
      long off = i - n_x;
      int which = (int)(off >> 20);
      long wo = off & (W_ELT - 1);
      if (which < 3) {
        src = (which == 0 ? wq : which == 1 ? wk : wv) + wo;
        dst = wqkv + which * W_ELT + wo;
      } else {
        src = wp + wo;
        dst = wpb + wo;
      }
    }
    float4 v = *(const float4*)src;
    ushort4 u;
    u.x = f2bf(v.x); u.y = f2bf(v.y); u.z = f2bf(v.z); u.w = f2bf(v.w);
    *(ushort4*)dst = u;
  }
  int t = blockIdx.x * blockDim.x + threadIdx.x;
  if (t < 3 * C_) {
    float v = t < C_ ? bq[t] : (t < 2 * C_ ? bk[t - C_] : bv[t - 2 * C_]);
    bias_cat[t] = v;
  }
  if (t < B_ * T_ / 2) {  // mask pair words: 0xFFFF per live key
    const int* mr = maskp + t * 2;
    mpair[t] = (mr[0] ? 0xFFFFu : 0u) | (mr[1] ? 0xFFFF0000u : 0u);
  }
}

// ---------------------------------------------------------------- GEMM (A @ B^T)
#define BM 128
#define BN 128
#define BK 32

template <int EPI>
__global__ __launch_bounds__(256, 2) void k_gemm(
    const unsigned short* __restrict__ A, const unsigned short* __restrict__ Bm,
    const float* __restrict__ bias, unsigned short* __restrict__ q_ws,
    unsigned short* __restrict__ k_ws, unsigned short* __restrict__ vt_ws,
    const float* __restrict__ xres, float* __restrict__ zout) {
  __shared__ unsigned short Al[2][BM * BK];  // 2 x 8 KB
  __shared__ unsigned short Bl[2][BN * BK];  // 2 x 8 KB
  const int tid = threadIdx.x, lane = tid & 63, w = tid >> 6;
  const int lc = lane & 15, lr = lane >> 4;
  const int m0 = blockIdx.y * BM, n0 = blockIdx.x * BN;
  const int wr = w >> 1, wc = w & 1;
  const char* Ab = (const char*)A;
  const char* Bb = (const char*)Bm;

  f32x4 acc[4][4] = {};

  auto stage = [&](int buf, int k0) {
#pragma unroll
    for (int it = 0; it < 2; ++it) {
      int f = it * 4096 + tid * 16;
      int row = f >> 6, colb = f & 63;
      gload_lds16(Ab + (long)(m0 + row) * (C_ * 2) + k0 * 2 + colb,
                  (char*)Al[buf] + it * 4096 + w * 1024);
      gload_lds16(Bb + (long)(n0 + row) * (C_ * 2) + k0 * 2 + colb,
                  (char*)Bl[buf] + it * 4096 + w * 1024);
    }
  };

  stage(0, 0);
  __syncthreads();
  int cur = 0;
  for (int k0 = 0; k0 < C_; k0 += BK) {
    if (k0 + BK < C_) stage(cur ^ 1, k0 + BK);  // prefetch under compute
    s16x8 af[4], bfr[4];
#pragma unroll
    for (int mf = 0; mf < 4; ++mf)
      af[mf] = *(const s16x8*)&Al[cur][(wr * 64 + mf * 16 + lc) * BK + lr * 8];
#pragma unroll
    for (int nf = 0; nf < 4; ++nf)
      bfr[nf] = *(const s16x8*)&Bl[cur][(wc * 64 + nf * 16 + lc) * BK + lr * 8];
#pragma unroll
    for (int mf = 0; mf < 4; ++mf)
#pragma unroll
      for (int nf = 0; nf < 4; ++nf)
        acc[mf][nf] = __builtin_amdgcn_mfma_f32_16x16x32_bf16(af[mf], bfr[nf],
                                                              acc[mf][nf], 0, 0, 0);
    __syncthreads();
    cur ^= 1;
  }

  if (EPI == 0) {
    // Q gets 1/8 (scale) * log2(e) so attention can use exp2 directly
#pragma unroll
    for (int mf = 0; mf < 4; ++mf)
#pragma unroll
      for (int nf = 0; nf < 4; ++nf) {
        int gn = n0 + wc * 64 + nf * 16 + lc;
        int which = gn >> 10, nn = gn & 1023;
        int hh = nn >> 6, dd = nn & 63;
        float bia = bias[gn];
        if (which == 2) {
          int gm = m0 + wr * 64 + mf * 16 + lr * 4;
          int bb = gm >> 10, tt = gm & 1023;
          ushort4 pk;
          pk.x = f2bf(acc[mf][nf][0] + bia);
          pk.y = f2bf(acc[mf][nf][1] + bia);
          pk.z = f2bf(acc[mf][nf][2] + bia);
          pk.w = f2bf(acc[mf][nf][3] + bia);
          *(ushort4*)&vt_ws[((long)(bb * H_ + hh) * HD + dd) * T_ + tt] = pk;
        } else {
          unsigned short* dst = (which == 0) ? q_ws : k_ws;
          float scl = (which == 0) ? 0.18033688011112042f : 1.0f;
#pragma unroll
          for (int i = 0; i < 4; ++i) {
            int gm = m0 + wr * 64 + mf * 16 + lr * 4 + i;
            int bb = gm >> 10, tt = gm & 1023;
            dst[((long)(bb * H_ + hh) * T_ + tt) * HD + dd] =
                f2bf((acc[mf][nf][i] + bia) * scl);
          }
        }
      }
  } else {
#pragma unroll
    for (int mf = 0; mf < 4; ++mf)
#pragma unroll
      for (int nf = 0; nf < 4; ++nf) {
        int gn = n0 + wc * 64 + nf * 16 + lc;
        float bia = bias[gn];
#pragma unroll
        for (int i = 0; i < 4; ++i) {
          int gm = m0 + wr * 64 + mf * 16 + lr * 4 + i;
          long idx = (long)gm * C_ + gn;
          zout[idx] = acc[mf][nf][i] + bia + xres[idx];
        }
      }
  }
}

// ---------------------------------------------------------------- attention
// Q,K: [B*H][T][64] bf16 (Q pre-scaled by log2(e)/8). Vt: [B*H][64][T] bf16.
// Swapped-operand flash attention: S^T = mfma(K,Q) puts each lane's 16 P
// values on ONE query (q = lane&15). P stays in registers: pack bf16 pairs,
// mask via AND, redistribute to PV B-fragments with 16 shfl + 8 selects.
// No P LDS buffer -> 32 KB LDS -> higher occupancy. K/V double-buffered,
// 2-phase prefetch. l via ones-MFMA; O^T layout; one rcp per lane.
__global__ __launch_bounds__(256, 4) void k_attn(
    const unsigned short* __restrict__ Qp, const unsigned short* __restrict__ Kp,
    const unsigned short* __restrict__ Vtp, const unsigned int* __restrict__ mpairp,
    unsigned short* __restrict__ Yp) {
  __shared__ unsigned short Kl[2][64 * 64];  // 2 x 8 KB, [key][d] swizzled
  __shared__ unsigned short Vl[2][64 * 64];  // 2 x 8 KB, [d][key] swizzled
  const int tid = threadIdx.x, lane = tid & 63, w = tid >> 6;
  const int bh = blockIdx.x >> 4, qt = blockIdx.x & 15;
  const int b = bh >> 4, h = bh & 15;
  const int lc = lane & 15, lr = lane >> 4;
  const int q0 = qt * 64 + w * 16;

  // Q frags (B-operand): lane holds Q[q0+lc][d = lr*8 + j (+32)]
  const unsigned short* qbase = Qp + ((long)bh * T_ + q0) * HD;
  s16x8 aq0 = *(const s16x8*)(qbase + lc * HD + lr * 8);
  s16x8 aq1 = *(const s16x8*)(qbase + lc * HD + 32 + lr * 8);

  s16x8 ones;
#pragma unroll
  for (int j = 0; j < 8; ++j) ones[j] = (short)0x3F80;  // bf16 1.0

  float m_run = -3e38f;
  f32x4 o[4] = {};   // O^T: row d = nf*16+lr*4+i, col q = lc
  f32x4 o_l = {};    // l[q=lc] replicated

  const char* kb_g = (const char*)(Kp + (long)bh * T_ * HD);
  const char* vb_g = (const char*)(Vtp + (long)bh * HD * T_);
  const unsigned int* mrow2 = mpairp + b * (T_ / 2);

  auto stage = [&](int buf, int kt) {
#pragma unroll
    for (int it = 0; it < 2; ++it) {
      int f = it * 4096 + w * 1024 + lane * 16;
      int row = f >> 7;
      int swz = (f & 127) ^ ((row & 7) << 4);
      gload_lds16(kb_g + (long)kt * 8192 + (f & ~127) + swz,
                  (char*)Kl[buf] + it * 4096 + w * 1024);
      gload_lds16(vb_g + (long)row * (T_ * 2) + kt * 128 + swz,
                  (char*)Vl[buf] + it * 4096 + w * 1024);
    }
  };

  stage(0, 0);
  __syncthreads();

  const int s01 = lc + ((lane & 16) << 1);  // lc + 32*(lr&1)
  const int s23 = s01 + 16;
  const bool hi = (lane >= 32);             // lr>>1

  int cur = 0;
  for (int kt = 0; kt < T_ / 64; ++kt) {
    if (kt + 1 < T_ / 64) stage(cur ^ 1, kt + 1);

    // S^T = K Q^T: s[kf][i] = S[key = 16kf+lr*4+i][q = lc]  (exp2 domain)
    f32x4 s[4];
    const char* kl = (const char*)Kl[cur];
#pragma unroll
    for (int kf = 0; kf < 4; ++kf) {
      int key = kf * 16 + lc;
      s16x8 kb0 = *(const s16x8*)(kl + ((key * 128 + lr * 16) ^ ((key & 7) << 4)));
      s16x8 kb1 = *(const s16x8*)(kl + ((key * 128 + 64 + lr * 16) ^ ((key & 7) << 4)));
      f32x4 z = {};
      z = __builtin_amdgcn_mfma_f32_16x16x32_bf16(kb0, aq0, z, 0, 0, 0);
      z = __builtin_amdgcn_mfma_f32_16x16x32_bf16(kb1, aq1, z, 0, 0, 0);
      s[kf] = z;
    }

    // mask pair words for this lane's 8 key-pairs
    unsigned int mw[4][2];
#pragma unroll
    for (int kf = 0; kf < 4; ++kf) {
      mw[kf][0] = mrow2[kt * 32 + kf * 8 + lr * 2];
      mw[kf][1] = mrow2[kt * 32 + kf * 8 + lr * 2 + 1];
    }

    // wave-wide max over UNMASKED S (any m >= true max is valid)
    float t0 = s[0][0];
#pragma unroll
    for (int kf = 0; kf < 4; ++kf)
#pragma unroll
      for (int i = 0; i < 4; ++i) t0 = fmaxf(t0, s[kf][i]);
#pragma unroll
    for (int d = 1; d < 64; d <<= 1) t0 = fmaxf(t0, __shfl_xor(t0, d, 64));

    // defer-max: rescale only when max grows by > 8 (P bounded by 2^8)
    if (t0 > m_run + 8.0f) {
      float sc = __builtin_amdgcn_exp2f(m_run - t0);
      m_run = t0;
#pragma unroll
      for (int nf = 0; nf < 4; ++nf)
#pragma unroll
        for (int i = 0; i < 4; ++i) o[nf][i] *= sc;
      o_l[0] *= sc;
    }

    // P = exp2(S - m); pack bf16 pairs (truncate); zero masked via AND
    unsigned int pk[4][2];
#pragma unroll
    for (int kf = 0; kf < 4; ++kf) {
      float p0 = __builtin_amdgcn_exp2f(s[kf][0] - m_run);
      float p1 = __builtin_amdgcn_exp2f(s[kf][1] - m_run);
      float p2 = __builtin_amdgcn_exp2f(s[kf][2] - m_run);
      float p3 = __builtin_amdgcn_exp2f(s[kf][3] - m_run);
      unsigned int u0 = __builtin_bit_cast(unsigned int, p0);
      unsigned int u1 = __builtin_bit_cast(unsigned int, p1);
      unsigned int u2 = __builtin_bit_cast(unsigned int, p2);
      unsigned int u3 = __builtin_bit_cast(unsigned int, p3);
      pk[kf][0] = ((u1 & 0xFFFF0000u) | (u0 >> 16)) & mw[kf][0];
      pk[kf][1] = ((u3 & 0xFFFF0000u) | (u2 >> 16)) & mw[kf][1];
    }

    // redistribute to PV B-frags: ap[kc] = P[q=lc][keys kc*32+lr*8 .. +7]
    s16x8 ap[2];
#pragma unroll
    for (int kc = 0; kc < 2; ++kc) {
      unsigned int A0 = pk[kc * 2][0], A1 = pk[kc * 2][1];
      unsigned int B0 = pk[kc * 2 + 1][0], B1 = pk[kc * 2 + 1][1];
      unsigned int w0a = __shfl((int)A0, s01, 64), w0b = __shfl((int)B0, s01, 64);
      unsigned int w1a = __shfl((int)A1, s01, 64), w1b = __shfl((int)B1, s01, 64);
      unsigned int w2a = __shfl((int)A0, s23, 64), w2b = __shfl((int)B0, s23, 64);
      unsigned int w3a = __shfl((int)A1, s23, 64), w3b = __shfl((int)B1, s23, 64);
      i32x4 wv;
      wv[0] = (int)(hi ? w0b : w0a);
      wv[1] = (int)(hi ? w1b : w1a);
      wv[2] = (int)(hi ? w2b : w2a);
      wv[3] = (int)(hi ? w3b : w3a);
      ap[kc] = __builtin_bit_cast(s16x8, wv);
    }

    // PV: o += V^T . P^T (A=V^T rows=d, B=P rows=q); l += ones . P^T
#pragma unroll
    for (int kc = 0; kc < 2; ++kc) {
      int koff = kc * 64 + lr * 16;
      o_l = __builtin_amdgcn_mfma_f32_16x16x32_bf16(ones, ap[kc], o_l, 0, 0, 0);
#pragma unroll
      for (int nf = 0; nf < 4; ++nf) {
        int drow = nf * 16 + lc;
        s16x8 vb = *(const s16x8*)((const char*)Vl[cur] +
                                   ((drow * 128 + koff) ^ ((drow & 7) << 4)));
        o[nf] = __builtin_amdgcn_mfma_f32_16x16x32_bf16(vb, ap[kc], o[nf], 0, 0, 0);
      }
    }
    __syncthreads();
    cur ^= 1;
  }

  // normalize + write y [B,T,C] bf16: row q = q0+lc, cols d = h*64+nf*16+lr*4+i
  float rl = 1.0f / o_l[0];
  unsigned short* yrow = Yp + ((long)(b * T_ + q0 + lc)) * C_ + h * 64;
#pragma unroll
  for (int nf = 0; nf < 4; ++nf) {
    ushort4 pw;
    pw.x = f2bf(o[nf][0] * rl);
    pw.y = f2bf(o[nf][1] * rl);
    pw.z = f2bf(o[nf][2] * rl);
    pw.w = f2bf(o[nf][3] * rl);
    *(ushort4*)(yrow + nf * 16 + lr * 4) = pw;
  }
}

// ---------------------------------------------------------------- LayerNorm
__global__ __launch_bounds__(256) void k_ln(const float* __restrict__ z,
                                            const float* __restrict__ lw,
                                            const float* __restrict__ lb,
                                            float* __restrict__ out) {
  const int row = blockIdx.x;
  float4 v = ((const float4*)(z + (long)row * C_))[threadIdx.x];
  float s = v.x + v.y + v.z + v.w;
  float s2 = v.x * v.x + v.y * v.y + v.z * v.z + v.w * v.w;
#pragma unroll
  for (int d = 1; d < 64; d <<= 1) {
    s += __shfl_xor(s, d, 64);
    s2 += __shfl_xor(s2, d, 64);
  }
  __shared__ float rs[4], rq[4];
  int wv_ = threadIdx.x >> 6;
  if ((threadIdx.x & 63) == 0) { rs[wv_] = s; rq[wv_] = s2; }
  __syncthreads();
  s = rs[0] + rs[1] + rs[2] + rs[3];
  s2 = rq[0] + rq[1] + rq[2] + rq[3];
  float mu = s * (1.0f / C_);
  float var = s2 * (1.0f / C_) - mu * mu;
  float inv = rsqrtf(var + 1e-12f);
  float4 wv4 = ((const float4*)lw)[threadIdx.x];
  float4 bv4 = ((const float4*)lb)[threadIdx.x];
  float4 ov;
  ov.x = (v.x - mu) * inv * wv4.x + bv4.x;
  ov.y = (v.y - mu) * inv * wv4.y + bv4.y;
  ov.z = (v.z - mu) * inv * wv4.z + bv4.z;
  ov.w = (v.w - mu) * inv * wv4.w + bv4.w;
  ((float4*)(out + (long)row * C_))[threadIdx.x] = ov;
}

// ---------------------------------------------------------------- launch
extern "C" void kernel_launch(void* const* d_in, const int* in_sizes, int n_in,
                              void* d_out, int out_size, void* d_ws,
                              size_t ws_size, hipStream_t stream) {
  const float* x = (const float*)d_in[0];
  const int* mask = (const int*)d_in[1];
  const float* Wq = (const float*)d_in[2];
  const float* bq = (const float*)d_in[3];
  const float* Wk = (const float*)d_in[4];
  const float* bk = (const float*)d_in[5];
  const float* Wv = (const float*)d_in[6];
  const float* bv = (const float*)d_in[7];
  const float* Wp = (const float*)d_in[8];
  const float* bp = (const float*)d_in[9];
  const float* lnw = (const float*)d_in[10];
  const float* lnb = (const float*)d_in[11];
  float* out = (float*)d_out;

  char* ws = (char*)d_ws;
  const size_t MB = 1024 * 1024;
  unsigned short* xb = (unsigned short*)(ws);             // 16 MB
  unsigned short* q_ws = (unsigned short*)(ws + 16 * MB); // 16 MB
  unsigned short* k_ws = (unsigned short*)(ws + 32 * MB); // 16 MB
  unsigned short* vt_ws = (unsigned short*)(ws + 48 * MB);// 16 MB
  unsigned short* y_ws = (unsigned short*)(ws + 64 * MB); // 16 MB
  unsigned short* wqkv = (unsigned short*)(ws + 80 * MB); // 6 MB
  unsigned short* wpb = (unsigned short*)(ws + 86 * MB);  // 2 MB
  float* bias_cat = (float*)(ws + 88 * MB);               // 12 KB
  unsigned int* mpair = (unsigned int*)(ws + 88 * MB + 16384);  // 16 KB
  float* z = (float*)(ws);  // 32 MB, aliases xb+q_ws (both dead by then)

  k_convert<<<dim3(2048), dim3(256), 0, stream>>>(x, Wq, Wk, Wv, Wp, bq, bk, bv,
                                                  mask, xb, wqkv, wpb, bias_cat,
                                                  mpair);
  k_gemm<0><<<dim3(24, 64), dim3(256), 0, stream>>>(
      xb, wqkv, bias_cat, q_ws, k_ws, vt_ws, nullptr, nullptr);
  k_attn<<<dim3(2048), dim3(256), 0, stream>>>(q_ws, k_ws, vt_ws, mpair, y_ws);
  k_gemm<1><<<dim3(8, 64), dim3(256), 0, stream>>>(
      y_ws, wpb, bp, nullptr, nullptr, nullptr, x, z);
  k_ln<<<dim3(8192), dim3(256), 0, stream>>>(z, lnw, lnb, out);
}